// Round 17
// baseline (1047.041 us; speedup 1.0000x reference)
//
#include <hip/hip_runtime.h>
#include <math.h>

#define DD 128
#define EDD 64

typedef __attribute__((ext_vector_type(8))) short bf16x8;
typedef __attribute__((ext_vector_type(4))) float f32x4;

__device__ inline unsigned short f2bf(float f) {
    unsigned int u = __float_as_uint(f);
    u += 0x7FFFu + ((u >> 16) & 1u);
    return (unsigned short)(u >> 16);
}
__device__ inline unsigned int pack2bf16(float lo, float hi) {
    return (unsigned int)f2bf(lo) | ((unsigned int)f2bf(hi) << 16);
}
__device__ inline float bflo(unsigned int u) { return __uint_as_float(u << 16); }
__device__ inline float bfhi(unsigned int u) { return __uint_as_float(u & 0xffff0000u); }

// ---------------- pack six [128][128] fp32 weights into bf16 MFMA B-fragment order ----------------
__global__ __launch_bounds__(256) void packw6_kernel(
    const float* __restrict__ w0, const float* __restrict__ w1, const float* __restrict__ w2,
    const float* __restrict__ w3, const float* __restrict__ w4, const float* __restrict__ w5,
    unsigned short* __restrict__ packed)   // 6 * DD*DD contiguous
{
    int which = blockIdx.y;
    const float* w = which == 0 ? w0 : which == 1 ? w1 : which == 2 ? w2
                   : which == 3 ? w3 : which == 4 ? w4 : w5;
    unsigned short* pk = packed + (size_t)which * DD * DD;
    int idx = blockIdx.x * 256 + threadIdx.x;
    if (idx >= DD * DD) return;
    int j    = idx & 7;
    int lane = (idx >> 3) & 63;
    int kt   = (idx >> 9) & 3;
    int ncf  = idx >> 11;
    int kk  = kt * 32 + (lane >> 4) * 8 + j;
    int col = ncf * 16 + (lane & 15);
    pk[idx] = f2bf(w[kk * DD + col]);
}

__device__ inline void gemm_b(const bf16x8 af[4][2], const unsigned short* __restrict__ packB,
                              int wc, int lane, f32x4 acc[2][4])
{
    #pragma unroll
    for (int i = 0; i < 2; i++)
        #pragma unroll
        for (int j = 0; j < 4; j++) acc[i][j] = (f32x4){0.f, 0.f, 0.f, 0.f};
    #pragma unroll
    for (int kt = 0; kt < 4; kt++) {
        #pragma unroll
        for (int nc = 0; nc < 4; nc++) {
            bf16x8 b = *(const bf16x8*)&packB[(((wc * 4 + nc) * 4 + kt) * 64 + lane) * 8];
            acc[0][nc] = __builtin_amdgcn_mfma_f32_16x16x32_bf16(af[kt][0], b, acc[0][nc], 0, 0, 0);
            acc[1][nc] = __builtin_amdgcn_mfma_f32_16x16x32_bf16(af[kt][1], b, acc[1][nc], 0, 0, 0);
        }
    }
}

// ---------------- fused q/k/v/skip linears via MFMA + per-node LN(x) precompute ----------------
__global__ __launch_bounds__(256, 4) void lin4_mfma_kernel(
    const float* __restrict__ x,
    const unsigned short* __restrict__ packBq, const float* __restrict__ bq,
    const unsigned short* __restrict__ packBk, const float* __restrict__ bk,
    const unsigned short* __restrict__ packBv, const float* __restrict__ bv,
    const unsigned short* __restrict__ packBs, const float* __restrict__ bs,
    const float* __restrict__ sn_g, const float* __restrict__ sn_b,
    float* __restrict__ q, unsigned short* __restrict__ kplane, unsigned short* __restrict__ vplane,
    float* __restrict__ pre, unsigned int* __restrict__ lnx, int N)
{
    __shared__ unsigned short sxs[64 * DD];   // 16 KB
    int tid = threadIdx.x;
    int lane = tid & 63, wid = tid >> 6;
    size_t m0 = (size_t)blockIdx.x * 64;

    {
        float g0 = sn_g[2 * lane], g1 = sn_g[2 * lane + 1];
        float b0 = sn_b[2 * lane], b1 = sn_b[2 * lane + 1];
        #pragma unroll
        for (int r = 0; r < 16; r++) {
            int tr = wid * 16 + r;
            size_t row = m0 + tr;
            float v0 = 0.f, v1 = 0.f;
            if (row < (size_t)N) {
                float2 xv = *(const float2*)&x[row * DD + 2 * lane];
                v0 = xv.x; v1 = xv.y;
            }
            unsigned int uidx = ((unsigned)(tr * 64 + lane)) ^ (((unsigned)tr & 7u) << 2);
            ((unsigned int*)sxs)[uidx] = pack2bf16(v0, v1);
            float s1 = v0 + v1, s2 = v0 * v0 + v1 * v1;
            #pragma unroll
            for (int o = 32; o >= 1; o >>= 1) { s1 += __shfl_xor(s1, o); s2 += __shfl_xor(s2, o); }
            float mean = s1 * (1.f / DD);
            float var  = s2 * (1.f / DD) - mean * mean;
            float rs = rsqrtf(var + 1e-5f);
            if (row < (size_t)N)
                lnx[row * 64 + lane] = pack2bf16((v0 - mean) * rs * g0 + b0,
                                                 (v1 - mean) * rs * g1 + b1);
        }
    }
    __syncthreads();

    int wr = wid >> 1, wc = wid & 1;
    int rA = wr * 32 + (lane & 15);
    int kb = (lane >> 4) * 8;

    bf16x8 af[4][2];
    #pragma unroll
    for (int kt = 0; kt < 4; kt++) {
        int k0 = kt * 32 + kb;
        af[kt][0] = *(const bf16x8*)&sxs[((rA)      * DD + k0) ^ ((rA & 7) << 3)];
        int rA1 = rA + 16;
        af[kt][1] = *(const bf16x8*)&sxs[((rA1)     * DD + k0) ^ ((rA1 & 7) << 3)];
    }

    f32x4 acc[2][4];
    int colb = wc * 64 + (lane & 15);
    int jrow = (lane >> 4) * 4;

    // ---- Q ----
    gemm_b(af, packBq, wc, lane, acc);
    #pragma unroll
    for (int mrf = 0; mrf < 2; mrf++) {
        int rbase = wr * 32 + mrf * 16 + jrow;
        #pragma unroll
        for (int nc = 0; nc < 4; nc++) {
            int col = colb + nc * 16;
            float bias = bq[col];
            #pragma unroll
            for (int j = 0; j < 4; j++) {
                size_t row = m0 + rbase + j;
                if (row < (size_t)N) q[row * DD + col] = acc[mrf][nc][j] + bias;
            }
        }
    }
    // ---- K (bf16 plane) ----
    gemm_b(af, packBk, wc, lane, acc);
    #pragma unroll
    for (int mrf = 0; mrf < 2; mrf++) {
        int rbase = wr * 32 + mrf * 16 + jrow;
        #pragma unroll
        for (int nc = 0; nc < 4; nc++) {
            int col = colb + nc * 16;
            float bias = bk[col];
            #pragma unroll
            for (int j = 0; j < 4; j++) {
                size_t row = m0 + rbase + j;
                if (row < (size_t)N) kplane[row * DD + col] = f2bf(acc[mrf][nc][j] + bias);
            }
        }
    }
    // ---- V (bf16 plane) ----
    gemm_b(af, packBv, wc, lane, acc);
    #pragma unroll
    for (int mrf = 0; mrf < 2; mrf++) {
        int rbase = wr * 32 + mrf * 16 + jrow;
        #pragma unroll
        for (int nc = 0; nc < 4; nc++) {
            int col = colb + nc * 16;
            float bias = bv[col];
            #pragma unroll
            for (int j = 0; j < 4; j++) {
                size_t row = m0 + rbase + j;
                if (row < (size_t)N) vplane[row * DD + col] = f2bf(acc[mrf][nc][j] + bias);
            }
        }
    }
    // ---- Skip ----
    gemm_b(af, packBs, wc, lane, acc);
    #pragma unroll
    for (int mrf = 0; mrf < 2; mrf++) {
        int rbase = wr * 32 + mrf * 16 + jrow;
        #pragma unroll
        for (int nc = 0; nc < 4; nc++) {
            int col = colb + nc * 16;
            float bias = bs[col];
            #pragma unroll
            for (int j = 0; j < 4; j++) {
                size_t row = m0 + rbase + j;
                if (row < (size_t)N)
                    pre[row * DD + col] = x[row * DD + col] + acc[mrf][nc][j] + bias;
            }
        }
    }
}

// ---------------- per-NODE MLP ----------------
__global__ __launch_bounds__(256, 4) void mlpnode_kernel(
    const unsigned int* __restrict__ lnx,
    const unsigned short* __restrict__ packB1, const float* __restrict__ p1b,
    const unsigned short* __restrict__ packB2, const float* __restrict__ p2b,
    unsigned short* __restrict__ fnode, int N)
{
    __shared__ unsigned short sxs[64 * DD];
    int tid = threadIdx.x;
    int lane = tid & 63, wid = tid >> 6;
    size_t m0 = (size_t)blockIdx.x * 64;

    #pragma unroll
    for (int r = 0; r < 16; r++) {
        int tr = wid * 16 + r;
        size_t row = m0 + tr;
        unsigned int val = (row < (size_t)N) ? lnx[row * 64 + lane] : 0u;
        unsigned int uidx = ((unsigned)(tr * 64 + lane)) ^ (((unsigned)tr & 7u) << 2);
        ((unsigned int*)sxs)[uidx] = val;
    }
    __syncthreads();

    int wr = wid >> 1, wc = wid & 1;
    int rA = wr * 32 + (lane & 15);
    int kb = (lane >> 4) * 8;

    f32x4 acc[2][4];
    #pragma unroll
    for (int i = 0; i < 2; i++)
        #pragma unroll
        for (int j = 0; j < 4; j++) acc[i][j] = (f32x4){0.f, 0.f, 0.f, 0.f};
    #pragma unroll
    for (int kt = 0; kt < 4; kt++) {
        int k0 = kt * 32 + kb;
        bf16x8 a0 = *(const bf16x8*)&sxs[((rA)  * DD + k0) ^ ((rA & 7) << 3)];
        int rA1 = rA + 16;
        bf16x8 a1 = *(const bf16x8*)&sxs[((rA1) * DD + k0) ^ ((rA1 & 7) << 3)];
        #pragma unroll
        for (int nc = 0; nc < 4; nc++) {
            bf16x8 b = *(const bf16x8*)&packB1[(((wc * 4 + nc) * 4 + kt) * 64 + lane) * 8];
            acc[0][nc] = __builtin_amdgcn_mfma_f32_16x16x32_bf16(a0, b, acc[0][nc], 0, 0, 0);
            acc[1][nc] = __builtin_amdgcn_mfma_f32_16x16x32_bf16(a1, b, acc[1][nc], 0, 0, 0);
        }
    }
    __syncthreads();

    {
        float bias1[4];
        #pragma unroll
        for (int nc = 0; nc < 4; nc++) bias1[nc] = p1b[wc * 64 + nc * 16 + (lane & 15)];
        #pragma unroll
        for (int mrf = 0; mrf < 2; mrf++) {
            int rbase = wr * 32 + mrf * 16 + (lane >> 4) * 4;
            #pragma unroll
            for (int nc = 0; nc < 4; nc++) {
                int col = wc * 64 + nc * 16 + (lane & 15);
                #pragma unroll
                for (int j = 0; j < 4; j++) {
                    float h = acc[mrf][nc][j] + bias1[nc];
                    h = h / (1.f + __expf(-h));
                    int rr = rbase + j;
                    sxs[(rr * DD + col) ^ ((rr & 7) << 3)] = f2bf(h);
                }
            }
        }
    }
    __syncthreads();

    f32x4 acc2[2][4];
    #pragma unroll
    for (int i = 0; i < 2; i++)
        #pragma unroll
        for (int j = 0; j < 4; j++) acc2[i][j] = (f32x4){0.f, 0.f, 0.f, 0.f};
    #pragma unroll
    for (int kt = 0; kt < 4; kt++) {
        int k0 = kt * 32 + kb;
        bf16x8 a0 = *(const bf16x8*)&sxs[((rA)  * DD + k0) ^ ((rA & 7) << 3)];
        int rA1 = rA + 16;
        bf16x8 a1 = *(const bf16x8*)&sxs[((rA1) * DD + k0) ^ ((rA1 & 7) << 3)];
        #pragma unroll
        for (int nc = 0; nc < 4; nc++) {
            bf16x8 b = *(const bf16x8*)&packB2[(((wc * 4 + nc) * 4 + kt) * 64 + lane) * 8];
            acc2[0][nc] = __builtin_amdgcn_mfma_f32_16x16x32_bf16(a0, b, acc2[0][nc], 0, 0, 0);
            acc2[1][nc] = __builtin_amdgcn_mfma_f32_16x16x32_bf16(a1, b, acc2[1][nc], 0, 0, 0);
        }
    }

    {
        float bias2[4];
        #pragma unroll
        for (int nc = 0; nc < 4; nc++) bias2[nc] = p2b[wc * 64 + nc * 16 + (lane & 15)];
        #pragma unroll
        for (int mrf = 0; mrf < 2; mrf++) {
            int rbase = wr * 32 + mrf * 16 + (lane >> 4) * 4;
            #pragma unroll
            for (int nc = 0; nc < 4; nc++) {
                int col = wc * 64 + nc * 16 + (lane & 15);
                #pragma unroll
                for (int j = 0; j < 4; j++) {
                    size_t row = m0 + rbase + j;
                    if (row < (size_t)N)
                        fnode[row * DD + col] = f2bf(acc2[mrf][nc][j] + bias2[nc]);
                }
            }
        }
    }
}

// ---------------- prep1: deg/cnt histograms + sequential bf16 cast of edge_attr ----------------
__global__ __launch_bounds__(256) void prep1_kernel(
    const int* __restrict__ dstA, const int* __restrict__ sub_ind,
    const float* __restrict__ edge_attr, unsigned int* __restrict__ ea16u,
    int* __restrict__ deg, int* __restrict__ cnt, int E, int M)
{
    size_t i = (size_t)blockIdx.x * blockDim.x + threadIdx.x;
    size_t stride = (size_t)gridDim.x * blockDim.x;
    size_t total = (size_t)E * 8;
    for (size_t t = i; t < total; t += stride) {
        size_t eid = t >> 3;
        int part = (int)(t & 7);
        const float4* s = (const float4*)&edge_attr[eid * EDD + part * 8];
        float4 a = s[0], b = s[1];
        uint4 o;
        o.x = pack2bf16(a.x, a.y); o.y = pack2bf16(a.z, a.w);
        o.z = pack2bf16(b.x, b.y); o.w = pack2bf16(b.z, b.w);
        *(uint4*)&ea16u[eid * 32 + part * 4] = o;
        if (part == 0) atomicAdd(&deg[dstA[eid]], 1);
        if (t < (size_t)M) atomicAdd(&cnt[sub_ind[t]], 1);
    }
}

// ---------------- parallel 3-phase exclusive scan (two arrays at once) ----------------
__global__ __launch_bounds__(1024) void bscan_kernel(
    const int* __restrict__ inA, const int* __restrict__ inB,
    int* __restrict__ exA, int* __restrict__ exB,
    int* __restrict__ bsA, int* __restrict__ bsB, int N)
{
    const int* in = blockIdx.y ? inB : inA;
    int* ex = blockIdx.y ? exB : exA;
    int* bs = blockIdx.y ? bsB : bsA;
    __shared__ int s[1024];
    int tid = threadIdx.x;
    int i = blockIdx.x * 1024 + tid;
    int val = (i < N) ? in[i] : 0;
    s[tid] = val; __syncthreads();
    for (int off = 1; off < 1024; off <<= 1) {
        int t = (tid >= off) ? s[tid - off] : 0;
        __syncthreads();
        s[tid] += t;
        __syncthreads();
    }
    if (i < N) ex[i] = s[tid] - val;
    if (tid == 1023) bs[blockIdx.x] = s[1023];
}

__global__ void bsum_kernel(int* __restrict__ bsA, int* __restrict__ bsB,
                            int* __restrict__ indptrA, int* __restrict__ indptrB,
                            int nb, int N)
{
    int which = threadIdx.x;
    if (which < 2) {
        int* bs = which ? bsB : bsA;
        int* indptr = which ? indptrB : indptrA;
        int run = 0;
        for (int b = 0; b < nb; b++) { int v = bs[b]; bs[b] = run; run += v; }
        indptr[N] = run;
    }
}

// bfix + degree-bucket histogram (for descending-degree node ordering)
__global__ void bfix_kernel(int* __restrict__ exA, int* __restrict__ fillA, const int* __restrict__ bsA,
                            int* __restrict__ exB, int* __restrict__ fillB, const int* __restrict__ bsB,
                            const int* __restrict__ deg, int* __restrict__ dbuck, int N)
{
    int i = blockIdx.x * blockDim.x + threadIdx.x;
    if (i < N) {
        int vA = exA[i] + bsA[i >> 10];
        exA[i] = vA; fillA[i] = vA;
        int vB = exB[i] + bsB[i >> 10];
        exB[i] = vB; fillB[i] = vB;
        int b = deg[i]; if (b > 1023) b = 1023;
        atomicAdd(&dbuck[b], 1);
    }
}

// reverse (descending-degree) exclusive scan of 1024 buckets
__global__ __launch_bounds__(1024) void dsortscan_kernel(const int* __restrict__ dbuck,
                                                         int* __restrict__ dfill)
{
    __shared__ int s[1024];
    int tid = threadIdx.x;
    int val = dbuck[1023 - tid];
    s[tid] = val; __syncthreads();
    for (int off = 1; off < 1024; off <<= 1) {
        int t = (tid >= off) ? s[tid - off] : 0;
        __syncthreads();
        s[tid] += t;
        __syncthreads();
    }
    dfill[1023 - tid] = s[tid] - val;
}

// ---------------- prep2: edge scatter + subgraph scatter + degree-order scatter ----------------
__global__ void prep2_kernel(
    const int* __restrict__ srcA, const int* __restrict__ dstA, int E,
    int* __restrict__ fill, int2* __restrict__ spair,
    const int* __restrict__ sub_nodes, const int* __restrict__ sub_ind, int M,
    int* __restrict__ sfill, int* __restrict__ snode,
    const int* __restrict__ deg, int* __restrict__ dfill, int* __restrict__ norder, int N)
{
    int i = blockIdx.x * blockDim.x + threadIdx.x;
    int stride = gridDim.x * blockDim.x;
    int total = M > E ? M : E;
    for (int t = i; t < total; t += stride) {
        if (t < E) {
            int d = dstA[t];
            int pos = atomicAdd(&fill[d], 1);
            spair[pos] = make_int2(srcA[t], t);
        }
        if (t < M) {
            int seg = sub_ind[t];
            int pos = atomicAdd(&sfill[seg], 1);
            snode[pos] = sub_nodes[t];
        }
        if (t < N) {
            int b = deg[t]; if (b > 1023) b = 1023;
            int pos = atomicAdd(&dfill[b], 1);
            norder[pos] = t;
        }
    }
}

// ---------------- qWe precompute (bf16-packed out) ----------------
__global__ __launch_bounds__(256) void qprep_kernel(
    const float* __restrict__ q, const float* __restrict__ We,
    unsigned int* __restrict__ qweU, int N)
{
    int tid = threadIdx.x;
    int wave = tid >> 6, lane = tid & 63;
    int n = blockIdx.x * 4 + wave;
    if (n >= N) return;
    int jj = lane & 7, g = lane >> 3;
    int hc0 = g * 16;
    const float4* qp = (const float4*)&q[(size_t)n * DD + hc0];
    float4 q0 = qp[0], q1 = qp[1], q2 = qp[2], q3 = qp[3];
    float qWe[8];
    #pragma unroll
    for (int r = 0; r < 8; r++) {
        const float4* wp = (const float4*)&We[(size_t)(8 * jj + r) * DD + hc0];
        float4 wa = wp[0], wb = wp[1], wc = wp[2], wd = wp[3];
        qWe[r] = q0.x * wa.x + q0.y * wa.y + q0.z * wa.z + q0.w * wa.w
               + q1.x * wb.x + q1.y * wb.y + q1.z * wb.z + q1.w * wb.w
               + q2.x * wc.x + q2.y * wc.y + q2.z * wc.z + q2.w * wc.w
               + q3.x * wd.x + q3.y * wd.y + q3.z * wd.z + q3.w * wd.w;
    }
    uint4 packed;
    packed.x = pack2bf16(qWe[0], qWe[1]);
    packed.y = pack2bf16(qWe[2], qWe[3]);
    packed.z = pack2bf16(qWe[4], qWe[5]);
    packed.w = pack2bf16(qWe[6], qWe[7]);
    *(uint4*)&qweU[(size_t)n * 256 + 4 * lane] = packed;
}

// ---------------- attention: 1 wave/node (degree-sorted), 4-edge unroll, bf16 ea + kv ----------------
__global__ __launch_bounds__(256, 4) void attn_kernel(
    const float* __restrict__ q,
    const unsigned int* __restrict__ kplane32, const unsigned int* __restrict__ vplane32,
    const unsigned int* __restrict__ ea16u, const unsigned int* __restrict__ qweU,
    const float* __restrict__ We, const float* __restrict__ be,
    const int* __restrict__ indptr, const int2* __restrict__ spair,
    const int* __restrict__ norder,
    float* __restrict__ pre, int N)
{
    int tid = threadIdx.x;
    int wave = tid >> 6, lane = tid & 63;
    int slot = blockIdx.x * 4 + wave;
    if (slot >= N) return;
    int n = norder[slot];

    int gbase = lane & 56;
    int jj = lane & 7;
    int c0 = lane * 2;

    float2 qv  = *(const float2*)&q[(size_t)n * DD + c0];
    float2 bev = *(const float2*)&be[c0];

    float t = qv.x * bev.x + qv.y * bev.y;
    t += __shfl_xor(t, 1); t += __shfl_xor(t, 2); t += __shfl_xor(t, 4);
    float qbe4 = t * 0.25f;

    uint4 qw = *(const uint4*)&qweU[(size_t)n * 256 + 4 * lane];
    float qwe0 = bflo(qw.x), qwe1 = bfhi(qw.x), qwe2 = bflo(qw.y), qwe3 = bfhi(qw.y);
    float qwe4 = bflo(qw.z), qwe5 = bfhi(qw.z), qwe6 = bflo(qw.w), qwe7 = bfhi(qw.w);

    int start = indptr[n], end = indptr[n + 1];
    float s = 0.f, av0 = 0.f, av1 = 0.f;
    float aea[8];
    #pragma unroll
    for (int r = 0; r < 8; r++) aea[r] = 0.f;

    int ii = start;
    for (; ii + 3 < end; ii += 4) {
        int2 se[4];
        #pragma unroll
        for (int u = 0; u < 4; u++) se[u] = spair[ii + u];
        uint4 ea[4];
        unsigned int ku[4], vu[4];
        #pragma unroll
        for (int u = 0; u < 4; u++) {
            ea[u] = *(const uint4*)&ea16u[(size_t)se[u].y * 32 + jj * 4];
            ku[u] = kplane32[(size_t)se[u].x * 64 + lane];
            vu[u] = vplane32[(size_t)se[u].x * 64 + lane];
        }
        float p[4];
        #pragma unroll
        for (int u = 0; u < 4; u++) {
            float part = qv.x * bflo(ku[u]) + qv.y * bfhi(ku[u])
                       + bflo(ea[u].x) * qwe0 + bfhi(ea[u].x) * qwe1
                       + bflo(ea[u].y) * qwe2 + bfhi(ea[u].y) * qwe3
                       + bflo(ea[u].z) * qwe4 + bfhi(ea[u].z) * qwe5
                       + bflo(ea[u].w) * qwe6 + bfhi(ea[u].w) * qwe7;
            part += __shfl_xor(part, 1);
            part += __shfl_xor(part, 2);
            part += __shfl_xor(part, 4);
            p[u] = __expf(part * 0.25f + qbe4);
        }
        #pragma unroll
        for (int u = 0; u < 4; u++) {
            s += p[u];
            av0 += p[u] * bflo(vu[u]);
            av1 += p[u] * bfhi(vu[u]);
            aea[0] += p[u] * bflo(ea[u].x); aea[1] += p[u] * bfhi(ea[u].x);
            aea[2] += p[u] * bflo(ea[u].y); aea[3] += p[u] * bfhi(ea[u].y);
            aea[4] += p[u] * bflo(ea[u].z); aea[5] += p[u] * bfhi(ea[u].z);
            aea[6] += p[u] * bflo(ea[u].w); aea[7] += p[u] * bfhi(ea[u].w);
        }
    }
    for (; ii < end; ii++) {
        int2 se = spair[ii];
        uint4 ea = *(const uint4*)&ea16u[(size_t)se.y * 32 + jj * 4];
        unsigned int ku = kplane32[(size_t)se.x * 64 + lane];
        unsigned int vu = vplane32[(size_t)se.x * 64 + lane];
        float part = qv.x * bflo(ku) + qv.y * bfhi(ku)
                   + bflo(ea.x) * qwe0 + bfhi(ea.x) * qwe1
                   + bflo(ea.y) * qwe2 + bfhi(ea.y) * qwe3
                   + bflo(ea.z) * qwe4 + bfhi(ea.z) * qwe5
                   + bflo(ea.w) * qwe6 + bfhi(ea.w) * qwe7;
        part += __shfl_xor(part, 1);
        part += __shfl_xor(part, 2);
        part += __shfl_xor(part, 4);
        float p = __expf(part * 0.25f + qbe4);
        s += p;
        av0 += p * bflo(vu);
        av1 += p * bfhi(vu);
        aea[0] += p * bflo(ea.x); aea[1] += p * bfhi(ea.x);
        aea[2] += p * bflo(ea.y); aea[3] += p * bfhi(ea.y);
        aea[4] += p * bflo(ea.z); aea[5] += p * bfhi(ea.z);
        aea[6] += p * bflo(ea.w); aea[7] += p * bfhi(ea.w);
    }

    if (end > start) {
        float inv = 1.f / s;
        float oe0 = 0.f, oe1 = 0.f;
        #pragma unroll
        for (int m = 0; m < 8; m++) {
            #pragma unroll
            for (int r = 0; r < 8; r++) {
                float a = __shfl(aea[r], gbase + m);
                float2 w = *(const float2*)&We[(size_t)(8 * m + r) * DD + c0];
                oe0 += a * w.x;
                oe1 += a * w.y;
            }
        }
        size_t o = (size_t)n * DD + c0;
        pre[o]     += (av0 + oe0) * inv + bev.x;
        pre[o + 1] += (av1 + oe1) * inv + bev.y;
    }
}

// ---------------- final: per-node wave; 4-way unrolled gather-mean + LN + SiLU ----------------
__global__ __launch_bounds__(256) void final2_kernel(
    const float* __restrict__ pre, const unsigned int* __restrict__ fnodeU,
    const int* __restrict__ sindptr, const int* __restrict__ snode,
    const float* __restrict__ on_g, const float* __restrict__ on_b,
    float* __restrict__ out, int N)
{
    int tid = threadIdx.x;
    int wave = tid >> 6, lane = tid & 63;
    int n = blockIdx.x * 4 + wave;
    if (n >= N) return;
    int c0 = 2 * lane;

    int start = sindptr[n], end = sindptr[n + 1];
    float sum0 = 0.f, sum1 = 0.f;
    int ii = start;
    for (; ii + 3 < end; ii += 4) {
        int n0 = snode[ii], n1 = snode[ii + 1], n2 = snode[ii + 2], n3 = snode[ii + 3];
        unsigned int u0 = fnodeU[(size_t)n0 * 64 + lane];
        unsigned int u1 = fnodeU[(size_t)n1 * 64 + lane];
        unsigned int u2 = fnodeU[(size_t)n2 * 64 + lane];
        unsigned int u3 = fnodeU[(size_t)n3 * 64 + lane];
        sum0 += bflo(u0) + bflo(u1) + bflo(u2) + bflo(u3);
        sum1 += bfhi(u0) + bfhi(u1) + bfhi(u2) + bfhi(u3);
    }
    for (; ii < end; ii++) {
        unsigned int u = fnodeU[(size_t)snode[ii] * 64 + lane];
        sum0 += bflo(u);
        sum1 += bfhi(u);
    }
    float inv = 1.f / fmaxf((float)(end - start), 1.f);

    float2 pv = *(const float2*)&pre[(size_t)n * DD + c0];
    float v0 = pv.x + sum0 * inv;
    float v1 = pv.y + sum1 * inv;

    float s1 = v0 + v1, s2 = v0 * v0 + v1 * v1;
    #pragma unroll
    for (int off = 32; off >= 1; off >>= 1) { s1 += __shfl_xor(s1, off); s2 += __shfl_xor(s2, off); }
    float mean = s1 * (1.f / DD);
    float var  = s2 * (1.f / DD) - mean * mean;
    float rs = rsqrtf(var + 1e-5f);

    float2 gv = *(const float2*)&on_g[c0];
    float2 bv = *(const float2*)&on_b[c0];
    float ov0 = (v0 - mean) * rs * gv.x + bv.x;
    float ov1 = (v1 - mean) * rs * gv.y + bv.y;
    float2 res;
    res.x = ov0 / (1.f + __expf(-ov0));
    res.y = ov1 / (1.f + __expf(-ov1));
    *(float2*)&out[(size_t)n * DD + c0] = res;
}

extern "C" void kernel_launch(void* const* d_in, const int* in_sizes, int n_in,
                              void* d_out, int out_size, void* d_ws, size_t ws_size,
                              hipStream_t stream)
{
    const float* x         = (const float*)d_in[0];
    const int*   edge_index= (const int*)  d_in[1];
    const float* edge_attr = (const float*)d_in[2];
    const int*   sub_nodes = (const int*)  d_in[3];
    const int*   sub_ind   = (const int*)  d_in[4];
    const float* Wq = (const float*)d_in[5];  const float* bq = (const float*)d_in[6];
    const float* Wk = (const float*)d_in[7];  const float* bk = (const float*)d_in[8];
    const float* Wv = (const float*)d_in[9];  const float* bv = (const float*)d_in[10];
    const float* We = (const float*)d_in[11]; const float* be = (const float*)d_in[12];
    const float* Ws = (const float*)d_in[13]; const float* bs = (const float*)d_in[14];
    const float* sn_g = (const float*)d_in[15]; const float* sn_b = (const float*)d_in[16];
    const float* p1w = (const float*)d_in[17]; const float* p1b = (const float*)d_in[18];
    const float* p2w = (const float*)d_in[19]; const float* p2b = (const float*)d_in[20];
    const float* on_g = (const float*)d_in[21]; const float* on_b = (const float*)d_in[22];

    int N = in_sizes[0] / DD;
    int E = in_sizes[1] / 2;
    int M = in_sizes[3];
    float* out = (float*)d_out;

    // packed weights: order [p1w, p2w, Wq, Wk, Wv, Ws]
    unsigned short* packAll = (unsigned short*)d_ws;
    unsigned short* packB1 = packAll;
    unsigned short* packB2 = packB1 + DD * DD;
    unsigned short* packBq = packB2 + DD * DD;
    unsigned short* packBk = packBq + DD * DD;
    unsigned short* packBv = packBk + DD * DD;
    unsigned short* packBs = packBv + DD * DD;
    size_t ND = (size_t)N * DD;
    float* q     = (float*)(packBs + DD * DD);
    unsigned short* kplane = (unsigned short*)(q + ND);
    unsigned short* vplane = kplane + ND;
    float* pre   = (float*)(vplane + ND);
    unsigned int* qweU  = (unsigned int*)(pre + ND);        // N*256
    unsigned int* lnx   = qweU + (size_t)N * 256;           // N*64
    unsigned int* fnode = lnx + (size_t)N * 64;             // N*64
    unsigned int* ea16u = fnode + (size_t)N * 64;           // E*32 (~102 MB)
    int2* spair  = (int2*)(ea16u + (size_t)E * 32);         // E
    int* indptr  = (int*)(spair + E);       // N+1
    int* fill    = indptr + (N + 1);        // N
    // zero block: deg, cnt, dbuck contiguous
    int* deg     = fill + N;                // N
    int* cnt     = deg + N;                 // N
    int* dbuck   = cnt + N;                 // 1024
    int* sindptr = dbuck + 1024;            // N+1
    int* sfill   = sindptr + (N + 1);       // N
    int* snode   = sfill + N;               // M
    int* bsA     = snode + M;               // 64
    int* bsB     = bsA + 64;                // 64
    int* dfill   = bsB + 64;                // 1024
    int* norder  = dfill + 1024;            // N

    const int* srcA = edge_index;
    const int* dstA = edge_index + E;

    int nb = (N + 1023) / 1024;

    hipMemsetAsync(deg, 0, ((size_t)2 * N + 1024) * sizeof(int), stream);

    {
        dim3 g(64, 6);
        packw6_kernel<<<g, 256, 0, stream>>>(p1w, p2w, Wq, Wk, Wv, Ws, packAll);
    }

    lin4_mfma_kernel<<<(N + 63) / 64, 256, 0, stream>>>(x, packBq, bq, packBk, bk, packBv, bv,
                                                        packBs, bs, sn_g, sn_b,
                                                        q, kplane, vplane, pre, lnx, N);
    mlpnode_kernel<<<(N + 63) / 64, 256, 0, stream>>>(lnx, packB1, p1b, packB2, p2b,
                                                      (unsigned short*)fnode, N);
    prep1_kernel<<<4096, 256, 0, stream>>>(dstA, sub_ind, edge_attr, ea16u, deg, cnt, E, M);
    {
        dim3 g(nb, 2);
        bscan_kernel<<<g, 1024, 0, stream>>>(deg, cnt, indptr, sindptr, bsA, bsB, N);
    }
    bsum_kernel<<<1, 64, 0, stream>>>(bsA, bsB, indptr, sindptr, nb, N);
    bfix_kernel<<<(N + 255) / 256, 256, 0, stream>>>(indptr, fill, bsA, sindptr, sfill, bsB,
                                                     deg, dbuck, N);
    dsortscan_kernel<<<1, 1024, 0, stream>>>(dbuck, dfill);
    prep2_kernel<<<2048, 256, 0, stream>>>(srcA, dstA, E, fill, spair,
                                           sub_nodes, sub_ind, M, sfill, snode,
                                           deg, dfill, norder, N);
    qprep_kernel<<<(N + 3) / 4, 256, 0, stream>>>(q, We, qweU, N);
    attn_kernel<<<(N + 3) / 4, 256, 0, stream>>>(q, (const unsigned int*)kplane,
                                                 (const unsigned int*)vplane, ea16u, qweU,
                                                 We, be, indptr, spair, norder, pre, N);
    final2_kernel<<<(N + 3) / 4, 256, 0, stream>>>(pre, fnode, sindptr, snode, on_g, on_b, out, N);
}

// Round 18
// 736.555 us; speedup vs baseline: 1.4215x; 1.4215x over previous
//
#include <hip/hip_runtime.h>
#include <math.h>

#define DD 128
#define EDD 64

typedef __attribute__((ext_vector_type(8))) short bf16x8;
typedef __attribute__((ext_vector_type(4))) float f32x4;

__device__ inline unsigned short f2bf(float f) {
    unsigned int u = __float_as_uint(f);
    u += 0x7FFFu + ((u >> 16) & 1u);
    return (unsigned short)(u >> 16);
}
__device__ inline unsigned int pack2bf16(float lo, float hi) {
    return (unsigned int)f2bf(lo) | ((unsigned int)f2bf(hi) << 16);
}
__device__ inline float bflo(unsigned int u) { return __uint_as_float(u << 16); }
__device__ inline float bfhi(unsigned int u) { return __uint_as_float(u & 0xffff0000u); }

// ---------------- pack six [128][128] fp32 weights into bf16 MFMA B-fragment order ----------------
__global__ __launch_bounds__(256) void packw6_kernel(
    const float* __restrict__ w0, const float* __restrict__ w1, const float* __restrict__ w2,
    const float* __restrict__ w3, const float* __restrict__ w4, const float* __restrict__ w5,
    unsigned short* __restrict__ packed)
{
    int which = blockIdx.y;
    const float* w = which == 0 ? w0 : which == 1 ? w1 : which == 2 ? w2
                   : which == 3 ? w3 : which == 4 ? w4 : w5;
    unsigned short* pk = packed + (size_t)which * DD * DD;
    int idx = blockIdx.x * 256 + threadIdx.x;
    if (idx >= DD * DD) return;
    int j    = idx & 7;
    int lane = (idx >> 3) & 63;
    int kt   = (idx >> 9) & 3;
    int ncf  = idx >> 11;
    int kk  = kt * 32 + (lane >> 4) * 8 + j;
    int col = ncf * 16 + (lane & 15);
    pk[idx] = f2bf(w[kk * DD + col]);
}

__device__ inline void gemm_b(const bf16x8 af[4][2], const unsigned short* __restrict__ packB,
                              int wc, int lane, f32x4 acc[2][4])
{
    #pragma unroll
    for (int i = 0; i < 2; i++)
        #pragma unroll
        for (int j = 0; j < 4; j++) acc[i][j] = (f32x4){0.f, 0.f, 0.f, 0.f};
    #pragma unroll
    for (int kt = 0; kt < 4; kt++) {
        #pragma unroll
        for (int nc = 0; nc < 4; nc++) {
            bf16x8 b = *(const bf16x8*)&packB[(((wc * 4 + nc) * 4 + kt) * 64 + lane) * 8];
            acc[0][nc] = __builtin_amdgcn_mfma_f32_16x16x32_bf16(af[kt][0], b, acc[0][nc], 0, 0, 0);
            acc[1][nc] = __builtin_amdgcn_mfma_f32_16x16x32_bf16(af[kt][1], b, acc[1][nc], 0, 0, 0);
        }
    }
}

// ---------------- fused q/k/v/skip linears via MFMA + per-node LN(x) precompute ----------------
__global__ __launch_bounds__(256, 4) void lin4_mfma_kernel(
    const float* __restrict__ x,
    const unsigned short* __restrict__ packBq, const float* __restrict__ bq,
    const unsigned short* __restrict__ packBk, const float* __restrict__ bk,
    const unsigned short* __restrict__ packBv, const float* __restrict__ bv,
    const unsigned short* __restrict__ packBs, const float* __restrict__ bs,
    const float* __restrict__ sn_g, const float* __restrict__ sn_b,
    float* __restrict__ q, unsigned short* __restrict__ kplane, unsigned short* __restrict__ vplane,
    float* __restrict__ pre, unsigned int* __restrict__ lnx, int N)
{
    __shared__ unsigned short sxs[64 * DD];   // 16 KB
    int tid = threadIdx.x;
    int lane = tid & 63, wid = tid >> 6;
    size_t m0 = (size_t)blockIdx.x * 64;

    {
        float g0 = sn_g[2 * lane], g1 = sn_g[2 * lane + 1];
        float b0 = sn_b[2 * lane], b1 = sn_b[2 * lane + 1];
        #pragma unroll
        for (int r = 0; r < 16; r++) {
            int tr = wid * 16 + r;
            size_t row = m0 + tr;
            float v0 = 0.f, v1 = 0.f;
            if (row < (size_t)N) {
                float2 xv = *(const float2*)&x[row * DD + 2 * lane];
                v0 = xv.x; v1 = xv.y;
            }
            unsigned int uidx = ((unsigned)(tr * 64 + lane)) ^ (((unsigned)tr & 7u) << 2);
            ((unsigned int*)sxs)[uidx] = pack2bf16(v0, v1);
            float s1 = v0 + v1, s2 = v0 * v0 + v1 * v1;
            #pragma unroll
            for (int o = 32; o >= 1; o >>= 1) { s1 += __shfl_xor(s1, o); s2 += __shfl_xor(s2, o); }
            float mean = s1 * (1.f / DD);
            float var  = s2 * (1.f / DD) - mean * mean;
            float rs = rsqrtf(var + 1e-5f);
            if (row < (size_t)N)
                lnx[row * 64 + lane] = pack2bf16((v0 - mean) * rs * g0 + b0,
                                                 (v1 - mean) * rs * g1 + b1);
        }
    }
    __syncthreads();

    int wr = wid >> 1, wc = wid & 1;
    int rA = wr * 32 + (lane & 15);
    int kb = (lane >> 4) * 8;

    bf16x8 af[4][2];
    #pragma unroll
    for (int kt = 0; kt < 4; kt++) {
        int k0 = kt * 32 + kb;
        af[kt][0] = *(const bf16x8*)&sxs[((rA)      * DD + k0) ^ ((rA & 7) << 3)];
        int rA1 = rA + 16;
        af[kt][1] = *(const bf16x8*)&sxs[((rA1)     * DD + k0) ^ ((rA1 & 7) << 3)];
    }

    f32x4 acc[2][4];
    int colb = wc * 64 + (lane & 15);
    int jrow = (lane >> 4) * 4;

    // ---- Q ----
    gemm_b(af, packBq, wc, lane, acc);
    #pragma unroll
    for (int mrf = 0; mrf < 2; mrf++) {
        int rbase = wr * 32 + mrf * 16 + jrow;
        #pragma unroll
        for (int nc = 0; nc < 4; nc++) {
            int col = colb + nc * 16;
            float bias = bq[col];
            #pragma unroll
            for (int j = 0; j < 4; j++) {
                size_t row = m0 + rbase + j;
                if (row < (size_t)N) q[row * DD + col] = acc[mrf][nc][j] + bias;
            }
        }
    }
    // ---- K (bf16 plane) ----
    gemm_b(af, packBk, wc, lane, acc);
    #pragma unroll
    for (int mrf = 0; mrf < 2; mrf++) {
        int rbase = wr * 32 + mrf * 16 + jrow;
        #pragma unroll
        for (int nc = 0; nc < 4; nc++) {
            int col = colb + nc * 16;
            float bias = bk[col];
            #pragma unroll
            for (int j = 0; j < 4; j++) {
                size_t row = m0 + rbase + j;
                if (row < (size_t)N) kplane[row * DD + col] = f2bf(acc[mrf][nc][j] + bias);
            }
        }
    }
    // ---- V (bf16 plane) ----
    gemm_b(af, packBv, wc, lane, acc);
    #pragma unroll
    for (int mrf = 0; mrf < 2; mrf++) {
        int rbase = wr * 32 + mrf * 16 + jrow;
        #pragma unroll
        for (int nc = 0; nc < 4; nc++) {
            int col = colb + nc * 16;
            float bias = bv[col];
            #pragma unroll
            for (int j = 0; j < 4; j++) {
                size_t row = m0 + rbase + j;
                if (row < (size_t)N) vplane[row * DD + col] = f2bf(acc[mrf][nc][j] + bias);
            }
        }
    }
    // ---- Skip ----
    gemm_b(af, packBs, wc, lane, acc);
    #pragma unroll
    for (int mrf = 0; mrf < 2; mrf++) {
        int rbase = wr * 32 + mrf * 16 + jrow;
        #pragma unroll
        for (int nc = 0; nc < 4; nc++) {
            int col = colb + nc * 16;
            float bias = bs[col];
            #pragma unroll
            for (int j = 0; j < 4; j++) {
                size_t row = m0 + rbase + j;
                if (row < (size_t)N)
                    pre[row * DD + col] = x[row * DD + col] + acc[mrf][nc][j] + bias;
            }
        }
    }
}

// ---------------- per-NODE MLP ----------------
__global__ __launch_bounds__(256, 4) void mlpnode_kernel(
    const unsigned int* __restrict__ lnx,
    const unsigned short* __restrict__ packB1, const float* __restrict__ p1b,
    const unsigned short* __restrict__ packB2, const float* __restrict__ p2b,
    unsigned short* __restrict__ fnode, int N)
{
    __shared__ unsigned short sxs[64 * DD];
    int tid = threadIdx.x;
    int lane = tid & 63, wid = tid >> 6;
    size_t m0 = (size_t)blockIdx.x * 64;

    #pragma unroll
    for (int r = 0; r < 16; r++) {
        int tr = wid * 16 + r;
        size_t row = m0 + tr;
        unsigned int val = (row < (size_t)N) ? lnx[row * 64 + lane] : 0u;
        unsigned int uidx = ((unsigned)(tr * 64 + lane)) ^ (((unsigned)tr & 7u) << 2);
        ((unsigned int*)sxs)[uidx] = val;
    }
    __syncthreads();

    int wr = wid >> 1, wc = wid & 1;
    int rA = wr * 32 + (lane & 15);
    int kb = (lane >> 4) * 8;

    f32x4 acc[2][4];
    #pragma unroll
    for (int i = 0; i < 2; i++)
        #pragma unroll
        for (int j = 0; j < 4; j++) acc[i][j] = (f32x4){0.f, 0.f, 0.f, 0.f};
    #pragma unroll
    for (int kt = 0; kt < 4; kt++) {
        int k0 = kt * 32 + kb;
        bf16x8 a0 = *(const bf16x8*)&sxs[((rA)  * DD + k0) ^ ((rA & 7) << 3)];
        int rA1 = rA + 16;
        bf16x8 a1 = *(const bf16x8*)&sxs[((rA1) * DD + k0) ^ ((rA1 & 7) << 3)];
        #pragma unroll
        for (int nc = 0; nc < 4; nc++) {
            bf16x8 b = *(const bf16x8*)&packB1[(((wc * 4 + nc) * 4 + kt) * 64 + lane) * 8];
            acc[0][nc] = __builtin_amdgcn_mfma_f32_16x16x32_bf16(a0, b, acc[0][nc], 0, 0, 0);
            acc[1][nc] = __builtin_amdgcn_mfma_f32_16x16x32_bf16(a1, b, acc[1][nc], 0, 0, 0);
        }
    }
    __syncthreads();

    {
        float bias1[4];
        #pragma unroll
        for (int nc = 0; nc < 4; nc++) bias1[nc] = p1b[wc * 64 + nc * 16 + (lane & 15)];
        #pragma unroll
        for (int mrf = 0; mrf < 2; mrf++) {
            int rbase = wr * 32 + mrf * 16 + (lane >> 4) * 4;
            #pragma unroll
            for (int nc = 0; nc < 4; nc++) {
                int col = wc * 64 + nc * 16 + (lane & 15);
                #pragma unroll
                for (int j = 0; j < 4; j++) {
                    float h = acc[mrf][nc][j] + bias1[nc];
                    h = h / (1.f + __expf(-h));
                    int rr = rbase + j;
                    sxs[(rr * DD + col) ^ ((rr & 7) << 3)] = f2bf(h);
                }
            }
        }
    }
    __syncthreads();

    f32x4 acc2[2][4];
    #pragma unroll
    for (int i = 0; i < 2; i++)
        #pragma unroll
        for (int j = 0; j < 4; j++) acc2[i][j] = (f32x4){0.f, 0.f, 0.f, 0.f};
    #pragma unroll
    for (int kt = 0; kt < 4; kt++) {
        int k0 = kt * 32 + kb;
        bf16x8 a0 = *(const bf16x8*)&sxs[((rA)  * DD + k0) ^ ((rA & 7) << 3)];
        int rA1 = rA + 16;
        bf16x8 a1 = *(const bf16x8*)&sxs[((rA1) * DD + k0) ^ ((rA1 & 7) << 3)];
        #pragma unroll
        for (int nc = 0; nc < 4; nc++) {
            bf16x8 b = *(const bf16x8*)&packB2[(((wc * 4 + nc) * 4 + kt) * 64 + lane) * 8];
            acc2[0][nc] = __builtin_amdgcn_mfma_f32_16x16x32_bf16(a0, b, acc2[0][nc], 0, 0, 0);
            acc2[1][nc] = __builtin_amdgcn_mfma_f32_16x16x32_bf16(a1, b, acc2[1][nc], 0, 0, 0);
        }
    }

    {
        float bias2[4];
        #pragma unroll
        for (int nc = 0; nc < 4; nc++) bias2[nc] = p2b[wc * 64 + nc * 16 + (lane & 15)];
        #pragma unroll
        for (int mrf = 0; mrf < 2; mrf++) {
            int rbase = wr * 32 + mrf * 16 + (lane >> 4) * 4;
            #pragma unroll
            for (int nc = 0; nc < 4; nc++) {
                int col = wc * 64 + nc * 16 + (lane & 15);
                #pragma unroll
                for (int j = 0; j < 4; j++) {
                    size_t row = m0 + rbase + j;
                    if (row < (size_t)N)
                        fnode[row * DD + col] = f2bf(acc2[mrf][nc][j] + bias2[nc]);
                }
            }
        }
    }
}

// ---------------- fused histogram: deg (over E) + cnt (over M) in one launch ----------------
__global__ void count2_kernel(const int* __restrict__ dstA, int E,
                              const int* __restrict__ sub_ind, int M,
                              int* __restrict__ deg, int* __restrict__ cnt)
{
    int i = blockIdx.x * blockDim.x + threadIdx.x;
    int stride = gridDim.x * blockDim.x;
    int total = E > M ? E : M;
    for (; i < total; i += stride) {
        if (i < E) atomicAdd(&deg[dstA[i]], 1);
        if (i < M) atomicAdd(&cnt[sub_ind[i]], 1);
    }
}

// ---------------- parallel 3-phase exclusive scan (two arrays at once) ----------------
__global__ __launch_bounds__(1024) void bscan_kernel(
    const int* __restrict__ inA, const int* __restrict__ inB,
    int* __restrict__ exA, int* __restrict__ exB,
    int* __restrict__ bsA, int* __restrict__ bsB, int N)
{
    const int* in = blockIdx.y ? inB : inA;
    int* ex = blockIdx.y ? exB : exA;
    int* bs = blockIdx.y ? bsB : bsA;
    __shared__ int s[1024];
    int tid = threadIdx.x;
    int i = blockIdx.x * 1024 + tid;
    int val = (i < N) ? in[i] : 0;
    s[tid] = val; __syncthreads();
    for (int off = 1; off < 1024; off <<= 1) {
        int t = (tid >= off) ? s[tid - off] : 0;
        __syncthreads();
        s[tid] += t;
        __syncthreads();
    }
    if (i < N) ex[i] = s[tid] - val;
    if (tid == 1023) bs[blockIdx.x] = s[1023];
}

__global__ void bsum_kernel(int* __restrict__ bsA, int* __restrict__ bsB,
                            int* __restrict__ indptrA, int* __restrict__ indptrB,
                            int nb, int N)
{
    int which = threadIdx.x;
    if (which < 2) {
        int* bs = which ? bsB : bsA;
        int* indptr = which ? indptrB : indptrA;
        int run = 0;
        for (int b = 0; b < nb; b++) { int v = bs[b]; bs[b] = run; run += v; }
        indptr[N] = run;
    }
}

__global__ void bfix_kernel(int* __restrict__ exA, int* __restrict__ fillA, const int* __restrict__ bsA,
                            int* __restrict__ exB, int* __restrict__ fillB, const int* __restrict__ bsB,
                            int N)
{
    int i = blockIdx.x * blockDim.x + threadIdx.x;
    if (i < N) {
        int vA = exA[i] + bsA[i >> 10];
        exA[i] = vA; fillA[i] = vA;
        int vB = exB[i] + bsB[i >> 10];
        exB[i] = vB; fillB[i] = vB;
    }
}

// ---------------- scatter edge (src,eid) pairs into dst-CSR ----------------
__global__ void escatter_kernel(const int* __restrict__ srcA, const int* __restrict__ dstA, int E,
                                int* __restrict__ fill, int2* __restrict__ spair)
{
    int i = blockIdx.x * blockDim.x + threadIdx.x;
    int stride = gridDim.x * blockDim.x;
    for (; i < E; i += stride) {
        int d = dstA[i];
        int pos = atomicAdd(&fill[d], 1);
        spair[pos] = make_int2(srcA[i], i);
    }
}

// ---------------- scatter subgraph node ids into segment-sorted order ----------------
__global__ void sscatter_kernel(const int* __restrict__ sub_nodes, const int* __restrict__ sub_ind,
                                int M, int* __restrict__ sfill, int* __restrict__ snode)
{
    int i = blockIdx.x * blockDim.x + threadIdx.x;
    int stride = gridDim.x * blockDim.x;
    for (; i < M; i += stride) {
        int seg = sub_ind[i];
        int pos = atomicAdd(&sfill[seg], 1);
        snode[pos] = sub_nodes[i];
    }
}

// ---------------- qWe precompute (bf16-packed out) ----------------
__global__ __launch_bounds__(256) void qprep_kernel(
    const float* __restrict__ q, const float* __restrict__ We,
    unsigned int* __restrict__ qweU, int N)
{
    int tid = threadIdx.x;
    int wave = tid >> 6, lane = tid & 63;
    int n = blockIdx.x * 4 + wave;
    if (n >= N) return;
    int jj = lane & 7, g = lane >> 3;
    int hc0 = g * 16;
    const float4* qp = (const float4*)&q[(size_t)n * DD + hc0];
    float4 q0 = qp[0], q1 = qp[1], q2 = qp[2], q3 = qp[3];
    float qWe[8];
    #pragma unroll
    for (int r = 0; r < 8; r++) {
        const float4* wp = (const float4*)&We[(size_t)(8 * jj + r) * DD + hc0];
        float4 wa = wp[0], wb = wp[1], wc = wp[2], wd = wp[3];
        qWe[r] = q0.x * wa.x + q0.y * wa.y + q0.z * wa.z + q0.w * wa.w
               + q1.x * wb.x + q1.y * wb.y + q1.z * wb.z + q1.w * wb.w
               + q2.x * wc.x + q2.y * wc.y + q2.z * wc.z + q2.w * wc.w
               + q3.x * wd.x + q3.y * wd.y + q3.z * wd.z + q3.w * wd.w;
    }
    uint4 packed;
    packed.x = pack2bf16(qWe[0], qWe[1]);
    packed.y = pack2bf16(qWe[2], qWe[3]);
    packed.z = pack2bf16(qWe[4], qWe[5]);
    packed.w = pack2bf16(qWe[6], qWe[7]);
    *(uint4*)&qweU[(size_t)n * 256 + 4 * lane] = packed;
}

// ---------------- attention: 1 wave/node, 4-edge unroll; fp32 edge_attr direct, bf16 kv planes ----------------
__global__ __launch_bounds__(256, 5) void attn_kernel(
    const float* __restrict__ q,
    const unsigned int* __restrict__ kplane32, const unsigned int* __restrict__ vplane32,
    const float* __restrict__ edge_attr, const unsigned int* __restrict__ qweU,
    const float* __restrict__ We, const float* __restrict__ be,
    const int* __restrict__ indptr, const int2* __restrict__ spair,
    float* __restrict__ pre, int N)
{
    int tid = threadIdx.x;
    int wave = tid >> 6, lane = tid & 63;
    int n = blockIdx.x * 4 + wave;
    if (n >= N) return;

    int gbase = lane & 56;
    int jj = lane & 7;
    int c0 = lane * 2;

    float2 qv  = *(const float2*)&q[(size_t)n * DD + c0];
    float2 bev = *(const float2*)&be[c0];

    float t = qv.x * bev.x + qv.y * bev.y;
    t += __shfl_xor(t, 1); t += __shfl_xor(t, 2); t += __shfl_xor(t, 4);
    float qbe4 = t * 0.25f;

    uint4 qw = *(const uint4*)&qweU[(size_t)n * 256 + 4 * lane];
    float qwe0 = bflo(qw.x), qwe1 = bfhi(qw.x), qwe2 = bflo(qw.y), qwe3 = bfhi(qw.y);
    float qwe4 = bflo(qw.z), qwe5 = bfhi(qw.z), qwe6 = bflo(qw.w), qwe7 = bfhi(qw.w);

    int start = indptr[n], end = indptr[n + 1];
    float s = 0.f, av0 = 0.f, av1 = 0.f;
    float aea[8];
    #pragma unroll
    for (int r = 0; r < 8; r++) aea[r] = 0.f;

    int ii = start;
    for (; ii + 3 < end; ii += 4) {
        int2 se[4];
        #pragma unroll
        for (int u = 0; u < 4; u++) se[u] = spair[ii + u];
        float4 ea0[4], ea1[4];
        unsigned int ku[4], vu[4];
        #pragma unroll
        for (int u = 0; u < 4; u++) {
            const float4* eap = (const float4*)&edge_attr[(size_t)se[u].y * EDD + 8 * jj];
            ea0[u] = eap[0];
            ea1[u] = eap[1];
            ku[u] = kplane32[(size_t)se[u].x * 64 + lane];
            vu[u] = vplane32[(size_t)se[u].x * 64 + lane];
        }
        float p[4];
        #pragma unroll
        for (int u = 0; u < 4; u++) {
            float part = qv.x * bflo(ku[u]) + qv.y * bfhi(ku[u])
                       + ea0[u].x * qwe0 + ea0[u].y * qwe1 + ea0[u].z * qwe2 + ea0[u].w * qwe3
                       + ea1[u].x * qwe4 + ea1[u].y * qwe5 + ea1[u].z * qwe6 + ea1[u].w * qwe7;
            part += __shfl_xor(part, 1);
            part += __shfl_xor(part, 2);
            part += __shfl_xor(part, 4);
            p[u] = __expf(part * 0.25f + qbe4);
        }
        #pragma unroll
        for (int u = 0; u < 4; u++) {
            s += p[u];
            av0 += p[u] * bflo(vu[u]);
            av1 += p[u] * bfhi(vu[u]);
            aea[0] += p[u] * ea0[u].x; aea[1] += p[u] * ea0[u].y;
            aea[2] += p[u] * ea0[u].z; aea[3] += p[u] * ea0[u].w;
            aea[4] += p[u] * ea1[u].x; aea[5] += p[u] * ea1[u].y;
            aea[6] += p[u] * ea1[u].z; aea[7] += p[u] * ea1[u].w;
        }
    }
    for (; ii < end; ii++) {
        int2 se = spair[ii];
        const float4* eap = (const float4*)&edge_attr[(size_t)se.y * EDD + 8 * jj];
        float4 ea0 = eap[0];
        float4 ea1 = eap[1];
        unsigned int ku = kplane32[(size_t)se.x * 64 + lane];
        unsigned int vu = vplane32[(size_t)se.x * 64 + lane];
        float part = qv.x * bflo(ku) + qv.y * bfhi(ku)
                   + ea0.x * qwe0 + ea0.y * qwe1 + ea0.z * qwe2 + ea0.w * qwe3
                   + ea1.x * qwe4 + ea1.y * qwe5 + ea1.z * qwe6 + ea1.w * qwe7;
        part += __shfl_xor(part, 1);
        part += __shfl_xor(part, 2);
        part += __shfl_xor(part, 4);
        float p = __expf(part * 0.25f + qbe4);
        s += p;
        av0 += p * bflo(vu);
        av1 += p * bfhi(vu);
        aea[0] += p * ea0.x; aea[1] += p * ea0.y; aea[2] += p * ea0.z; aea[3] += p * ea0.w;
        aea[4] += p * ea1.x; aea[5] += p * ea1.y; aea[6] += p * ea1.z; aea[7] += p * ea1.w;
    }

    if (end > start) {
        float inv = 1.f / s;
        float oe0 = 0.f, oe1 = 0.f;
        #pragma unroll
        for (int m = 0; m < 8; m++) {
            #pragma unroll
            for (int r = 0; r < 8; r++) {
                float a = __shfl(aea[r], gbase + m);
                float2 w = *(const float2*)&We[(size_t)(8 * m + r) * DD + c0];
                oe0 += a * w.x;
                oe1 += a * w.y;
            }
        }
        size_t o = (size_t)n * DD + c0;
        pre[o]     += (av0 + oe0) * inv + bev.x;
        pre[o + 1] += (av1 + oe1) * inv + bev.y;
    }
}

// ---------------- final: per-node wave; 4-way unrolled gather-mean + LN + SiLU ----------------
__global__ __launch_bounds__(256) void final2_kernel(
    const float* __restrict__ pre, const unsigned int* __restrict__ fnodeU,
    const int* __restrict__ sindptr, const int* __restrict__ snode,
    const float* __restrict__ on_g, const float* __restrict__ on_b,
    float* __restrict__ out, int N)
{
    int tid = threadIdx.x;
    int wave = tid >> 6, lane = tid & 63;
    int n = blockIdx.x * 4 + wave;
    if (n >= N) return;
    int c0 = 2 * lane;

    int start = sindptr[n], end = sindptr[n + 1];
    float sum0 = 0.f, sum1 = 0.f;
    int ii = start;
    for (; ii + 3 < end; ii += 4) {
        int n0 = snode[ii], n1 = snode[ii + 1], n2 = snode[ii + 2], n3 = snode[ii + 3];
        unsigned int u0 = fnodeU[(size_t)n0 * 64 + lane];
        unsigned int u1 = fnodeU[(size_t)n1 * 64 + lane];
        unsigned int u2 = fnodeU[(size_t)n2 * 64 + lane];
        unsigned int u3 = fnodeU[(size_t)n3 * 64 + lane];
        sum0 += bflo(u0) + bflo(u1) + bflo(u2) + bflo(u3);
        sum1 += bfhi(u0) + bfhi(u1) + bfhi(u2) + bfhi(u3);
    }
    for (; ii < end; ii++) {
        unsigned int u = fnodeU[(size_t)snode[ii] * 64 + lane];
        sum0 += bflo(u);
        sum1 += bfhi(u);
    }
    float inv = 1.f / fmaxf((float)(end - start), 1.f);

    float2 pv = *(const float2*)&pre[(size_t)n * DD + c0];
    float v0 = pv.x + sum0 * inv;
    float v1 = pv.y + sum1 * inv;

    float s1 = v0 + v1, s2 = v0 * v0 + v1 * v1;
    #pragma unroll
    for (int off = 32; off >= 1; off >>= 1) { s1 += __shfl_xor(s1, off); s2 += __shfl_xor(s2, off); }
    float mean = s1 * (1.f / DD);
    float var  = s2 * (1.f / DD) - mean * mean;
    float rs = rsqrtf(var + 1e-5f);

    float2 gv = *(const float2*)&on_g[c0];
    float2 bv = *(const float2*)&on_b[c0];
    float ov0 = (v0 - mean) * rs * gv.x + bv.x;
    float ov1 = (v1 - mean) * rs * gv.y + bv.y;
    float2 res;
    res.x = ov0 / (1.f + __expf(-ov0));
    res.y = ov1 / (1.f + __expf(-ov1));
    *(float2*)&out[(size_t)n * DD + c0] = res;
}

extern "C" void kernel_launch(void* const* d_in, const int* in_sizes, int n_in,
                              void* d_out, int out_size, void* d_ws, size_t ws_size,
                              hipStream_t stream)
{
    const float* x         = (const float*)d_in[0];
    const int*   edge_index= (const int*)  d_in[1];
    const float* edge_attr = (const float*)d_in[2];
    const int*   sub_nodes = (const int*)  d_in[3];
    const int*   sub_ind   = (const int*)  d_in[4];
    const float* Wq = (const float*)d_in[5];  const float* bq = (const float*)d_in[6];
    const float* Wk = (const float*)d_in[7];  const float* bk = (const float*)d_in[8];
    const float* Wv = (const float*)d_in[9];  const float* bv = (const float*)d_in[10];
    const float* We = (const float*)d_in[11]; const float* be = (const float*)d_in[12];
    const float* Ws = (const float*)d_in[13]; const float* bs = (const float*)d_in[14];
    const float* sn_g = (const float*)d_in[15]; const float* sn_b = (const float*)d_in[16];
    const float* p1w = (const float*)d_in[17]; const float* p1b = (const float*)d_in[18];
    const float* p2w = (const float*)d_in[19]; const float* p2b = (const float*)d_in[20];
    const float* on_g = (const float*)d_in[21]; const float* on_b = (const float*)d_in[22];

    int N = in_sizes[0] / DD;
    int E = in_sizes[1] / 2;
    int M = in_sizes[3];
    float* out = (float*)d_out;

    unsigned short* packAll = (unsigned short*)d_ws;   // [p1w, p2w, Wq, Wk, Wv, Ws]
    unsigned short* packB1 = packAll;
    unsigned short* packB2 = packB1 + DD * DD;
    unsigned short* packBq = packB2 + DD * DD;
    unsigned short* packBk = packBq + DD * DD;
    unsigned short* packBv = packBk + DD * DD;
    unsigned short* packBs = packBv + DD * DD;
    size_t ND = (size_t)N * DD;
    float* q     = (float*)(packBs + DD * DD);
    unsigned short* kplane = (unsigned short*)(q + ND);
    unsigned short* vplane = kplane + ND;
    float* pre   = (float*)(vplane + ND);
    unsigned int* qweU  = (unsigned int*)(pre + ND);        // N*256
    unsigned int* lnx   = qweU + (size_t)N * 256;           // N*64
    unsigned int* fnode = lnx + (size_t)N * 64;             // N*64
    int2* spair  = (int2*)(fnode + (size_t)N * 64);         // E
    int* indptr  = (int*)(spair + E);       // N+1
    int* fill    = indptr + (N + 1);        // N
    int* deg     = fill + N;                // N   (zero block start)
    int* cnt     = deg + N;                 // N
    int* sindptr = cnt + N;                 // N+1
    int* sfill   = sindptr + (N + 1);       // N
    int* snode   = sfill + N;               // M
    int* bsA     = snode + M;               // 64
    int* bsB     = bsA + 64;                // 64

    const int* srcA = edge_index;
    const int* dstA = edge_index + E;

    int nb = (N + 1023) / 1024;

    hipMemsetAsync(deg, 0, (size_t)2 * N * sizeof(int), stream);

    {
        dim3 g(64, 6);
        packw6_kernel<<<g, 256, 0, stream>>>(p1w, p2w, Wq, Wk, Wv, Ws, packAll);
    }

    lin4_mfma_kernel<<<(N + 63) / 64, 256, 0, stream>>>(x, packBq, bq, packBk, bk, packBv, bv,
                                                        packBs, bs, sn_g, sn_b,
                                                        q, kplane, vplane, pre, lnx, N);
    mlpnode_kernel<<<(N + 63) / 64, 256, 0, stream>>>(lnx, packB1, p1b, packB2, p2b,
                                                      (unsigned short*)fnode, N);
    count2_kernel<<<2048, 256, 0, stream>>>(dstA, E, sub_ind, M, deg, cnt);
    {
        dim3 g(nb, 2);
        bscan_kernel<<<g, 1024, 0, stream>>>(deg, cnt, indptr, sindptr, bsA, bsB, N);
    }
    bsum_kernel<<<1, 64, 0, stream>>>(bsA, bsB, indptr, sindptr, nb, N);
    bfix_kernel<<<(N + 255) / 256, 256, 0, stream>>>(indptr, fill, bsA, sindptr, sfill, bsB, N);
    escatter_kernel<<<2048, 256, 0, stream>>>(srcA, dstA, E, fill, spair);
    sscatter_kernel<<<2048, 256, 0, stream>>>(sub_nodes, sub_ind, M, sfill, snode);
    qprep_kernel<<<(N + 3) / 4, 256, 0, stream>>>(q, We, qweU, N);
    attn_kernel<<<(N + 3) / 4, 256, 0, stream>>>(q, (const unsigned int*)kplane,
                                                 (const unsigned int*)vplane, edge_attr, qweU,
                                                 We, be, indptr, spair, pre, N);
    final2_kernel<<<(N + 3) / 4, 256, 0, stream>>>(pre, fnode, sindptr, snode, on_g, on_b, out, N);
}